// Round 5
// baseline (615.022 us; speedup 1.0000x reference)
//
#include <hip/hip_runtime.h>
#include <math.h>

#define TT 4096
#define BB 32
#define HH 512
#define CC 32000
#define NCHUNK 64     // t-chunks in phase A
#define TPC 64        // t per chunk (4 waves x 16 rows)
#define NBLK 1024     // co-resident: 256 CU x 4 blocks (enforced by launch_bounds)
#define NTHR 256
#define NTASK_A 2048  // (chunk,b) tasks
#define NTASK_C 1000  // (cblk 125) x (oct 8)
#define OSLICE (BB*CC)  // 1,024,000

// ws float offsets
#define WS_BAR    0         // 16 floats (2 uints used)
#define WS_CTX    16        // 16384
#define WS_LPART  16400     // 2048
#define WS_CPART  18448     // 32*64*512 = 1,048,576
#define WS_OPART  1067024   // 8*1,024,000 = 8,192,000

__device__ __forceinline__ float dot4(const float4 a, const float4 b) {
  return fmaf(a.w, b.w, fmaf(a.z, b.z, fmaf(a.y, b.y, fmaf(a.x, b.x, 0.f))));
}

// device-scope arrive+wait barrier; all NBLK blocks co-resident by construction
__device__ __forceinline__ void grid_barrier(unsigned* bar) {
  __syncthreads();
  if (threadIdx.x == 0) {
    const unsigned g = __hip_atomic_load(&bar[1], __ATOMIC_ACQUIRE, __HIP_MEMORY_SCOPE_AGENT);
    const unsigned arr = __hip_atomic_fetch_add(&bar[0], 1u, __ATOMIC_ACQ_REL, __HIP_MEMORY_SCOPE_AGENT);
    if (arr == NBLK - 1u) {
      __hip_atomic_store(&bar[0], 0u, __ATOMIC_RELAXED, __HIP_MEMORY_SCOPE_AGENT);
      __hip_atomic_fetch_add(&bar[1], 1u, __ATOMIC_RELEASE, __HIP_MEMORY_SCOPE_AGENT);
    } else {
      while (__hip_atomic_load(&bar[1], __ATOMIC_ACQUIRE, __HIP_MEMORY_SCOPE_AGENT) == g) {
        __builtin_amdgcn_s_sleep(1);
      }
    }
  }
  __syncthreads();
}

__global__ __launch_bounds__(NTHR, 4) void mega(
    const float* __restrict__ dec, const float* __restrict__ aw,
    const float* __restrict__ abp, const float* __restrict__ ow,
    const float* __restrict__ ob, float* __restrict__ out,
    float* __restrict__ ws)
{
  __shared__ float sh[2052];   // phase A: [4][512] ctx + [4] l; phase C: ctx stage [32][64]
  unsigned* bar = (unsigned*)(ws + WS_BAR);
  float* ctx   = ws + WS_CTX;
  float* lpart = ws + WS_LPART;
  float* cpart = ws + WS_CPART;
  float* opart = ws + WS_OPART;

  const int bid = blockIdx.x, tid = threadIdx.x;
  const int wv = tid >> 6, ln = tid & 63;

  // ================= Phase A: score + weighted partial sums =================
  {
    const float ab = abp[0];
    const float4 aw0 = *(const float4*)(aw + ln*8);
    const float4 aw1 = *(const float4*)(aw + ln*8 + 4);
    const size_t rowstep = (size_t)BB*HH;

    for (int task = bid; task < NTASK_A; task += NBLK) {
      const int chunk = task & 63, b = task >> 6;
      const float* base = dec + ((size_t)(chunk*TPC + wv*16)*BB + b)*HH + (size_t)ln*8;

      float4 A0[4], A1[4], B0[4], B1[4];
      float4 c0 = make_float4(0.f,0.f,0.f,0.f), c1 = make_float4(0.f,0.f,0.f,0.f);
      float l = 0.f;

      auto LD = [&](float4* X0, float4* X1, int i0) {
        #pragma unroll
        for (int j = 0; j < 4; ++j) {
          const float* p = base + (size_t)(i0 + j) * rowstep;
          X0[j] = *(const float4*)p;
          X1[j] = *(const float4*)(p + 4);
        }
      };
      auto CMP = [&](const float4* X0, const float4* X1) {
        float d[4];
        #pragma unroll
        for (int j = 0; j < 4; ++j) d[j] = dot4(X0[j], aw0) + dot4(X1[j], aw1);
        #pragma unroll
        for (int off = 32; off > 0; off >>= 1) {
          #pragma unroll
          for (int j = 0; j < 4; ++j) d[j] += __shfl_xor(d[j], off);
        }
        #pragma unroll
        for (int j = 0; j < 4; ++j) {
          const float ex = __expf(2.f*(d[j] + ab));
          const float th = 1.f - 2.f*__builtin_amdgcn_rcpf(ex + 1.f);
          const float w  = __expf(th);
          l += w;
          c0.x = fmaf(w, X0[j].x, c0.x); c0.y = fmaf(w, X0[j].y, c0.y);
          c0.z = fmaf(w, X0[j].z, c0.z); c0.w = fmaf(w, X0[j].w, c0.w);
          c1.x = fmaf(w, X1[j].x, c1.x); c1.y = fmaf(w, X1[j].y, c1.y);
          c1.z = fmaf(w, X1[j].z, c1.z); c1.w = fmaf(w, X1[j].w, c1.w);
        }
      };

      LD(A0, A1, 0);
      LD(B0, B1, 4);
      CMP(A0, A1);
      LD(A0, A1, 8);
      CMP(B0, B1);
      LD(B0, B1, 12);
      CMP(A0, A1);
      CMP(B0, B1);

      __syncthreads();   // sh reuse across tasks
      *(float4*)&sh[wv*HH + ln*8]     = c0;
      *(float4*)&sh[wv*HH + ln*8 + 4] = c1;
      if (ln == 0) sh[2048 + wv] = l;
      __syncthreads();
      if (tid < 128) {
        const int h = tid * 4;
        float4 a = make_float4(0.f,0.f,0.f,0.f);
        #pragma unroll
        for (int w2 = 0; w2 < 4; ++w2) {
          const float4 v = *(const float4*)&sh[w2*HH + h];
          a.x += v.x; a.y += v.y; a.z += v.z; a.w += v.w;
        }
        const size_t pp = (size_t)b*NCHUNK + chunk;
        *(float4*)(cpart + pp*HH + h) = a;
        if (tid == 0) lpart[pp] = sh[2048] + sh[2049] + sh[2050] + sh[2051];
      }
    }
  }
  grid_barrier(bar);

  // ================= Phase B: combine partials -> normalized ctx ============
  if (bid < BB) {
    const int b = bid;
    // L: lane-dependent vector loads (avoid scalar-cache cross-block hazard)
    float Lv = lpart[b*NCHUNK + ln];
    #pragma unroll
    for (int off = 32; off > 0; off >>= 1) Lv += __shfl_xor(Lv, off);
    float ax = 0.f, ay = 0.f;
    const float* basep = cpart + (size_t)b*NCHUNK*HH + tid*2;
    #pragma unroll 8
    for (int p = 0; p < NCHUNK; ++p) {
      const float2 v = *(const float2*)(basep + (size_t)p*HH);
      ax += v.x; ay += v.y;
    }
    const float inv = 1.f / Lv;
    *(float2*)(ctx + (size_t)b*HH + tid*2) = make_float2(ax*inv, ay*inv);
  }
  grid_barrier(bar);

  // ================= Phase C: out_part = ctx @ out_w^T (oct h-split) ========
  if (bid < NTASK_C) {
    const int cblk = bid >> 3, oct = bid & 7;
    const int c = cblk*256 + tid;
    const int h0 = oct*64;
    // stage ctx[:, h0:h0+64] to LDS (vector loads; lanes cover [32][64])
    {
      const int j = tid*8;           // 256*8 = 2048
      const int b = j >> 6, hh = j & 63;
      const float4 v0 = *(const float4*)(ctx + (size_t)b*HH + h0 + hh);
      const float4 v1 = *(const float4*)(ctx + (size_t)b*HH + h0 + hh + 4);
      *(float4*)(sh + j)     = v0;
      *(float4*)(sh + j + 4) = v1;
    }
    __syncthreads();
    float acc[BB];
    #pragma unroll
    for (int b = 0; b < BB; ++b) acc[b] = 0.f;
    const float* wrow = ow + (size_t)c*HH + h0;
    #pragma unroll 4
    for (int hh = 0; hh < 64; hh += 4) {
      const float4 w4 = *(const float4*)(wrow + hh);
      #pragma unroll
      for (int b = 0; b < BB; ++b) {
        const float4 c4 = *(const float4*)(sh + b*64 + hh);
        acc[b] = fmaf(w4.w, c4.w, fmaf(w4.z, c4.z, fmaf(w4.y, c4.y, fmaf(w4.x, c4.x, acc[b]))));
      }
    }
    #pragma unroll
    for (int b = 0; b < BB; ++b)
      opart[(size_t)oct*OSLICE + (size_t)b*CC + c] = acc[b];
  }
  grid_barrier(bar);

  // ================= Phase D: sum octs + bias -> out ========================
  {
    const size_t i = ((size_t)bid*NTHR + tid) * 4;
    if (i < (size_t)OSLICE) {
      float4 r = *(const float4*)(opart + i);
      #pragma unroll
      for (int q = 1; q < 8; ++q) {
        const float4 p = *(const float4*)(opart + (size_t)q*OSLICE + i);
        r.x += p.x; r.y += p.y; r.z += p.z; r.w += p.w;
      }
      const int cIdx = (int)(i % CC);
      const float4 b4 = *(const float4*)(ob + cIdx);
      *(float4*)(out + i) = make_float4(r.x+b4.x, r.y+b4.y, r.z+b4.z, r.w+b4.w);
    }
  }
}

extern "C" void kernel_launch(void* const* d_in, const int* in_sizes, int n_in,
                              void* d_out, int out_size, void* d_ws, size_t ws_size,
                              hipStream_t stream) {
  const float* dec = (const float*)d_in[0];
  const float* aw  = (const float*)d_in[1];
  const float* ab  = (const float*)d_in[2];
  const float* ow  = (const float*)d_in[3];
  const float* ob  = (const float*)d_in[4];
  float* out = (float*)d_out;
  float* ws  = (float*)d_ws;

  // zero the barrier state (ws is poisoned 0xAA; barrier needs 0 each launch)
  hipMemsetAsync(ws, 0, 64, stream);
  mega<<<dim3(NBLK), NTHR, 0, stream>>>(dec, aw, ab, ow, ob, out, ws);
}

// Round 6
// 136.871 us; speedup vs baseline: 4.4934x; 4.4934x over previous
//
#include <hip/hip_runtime.h>
#include <hip/hip_bf16.h>
#include <math.h>

#define TT 4096
#define BB 32
#define HH 512
#define CC 32000
#define NCHUNK 64   // t-chunks (TT/TPC)
#define TPC 64      // t per chunk (4 waves x 16 rows)

// ws layout (float offsets)
#define WS_CTX    0          // 32*512 = 16384 floats (k2->k3)
#define WS_LPART  16384      // 32*64 = 2048 floats (k1->k2)
#define WS_BIG    18432      // ctx_part 32*64*512=1,048,576 f; then out_part 2*32*32000=2,048,000 f

__device__ __forceinline__ float dot4(const float4 a, const float4 b) {
  return fmaf(a.w, b.w, fmaf(a.z, b.z, fmaf(a.y, b.y, fmaf(a.x, b.x, 0.f))));
}

// ---------------- k1: fused score + weighted partial sums ------------------
// PACKED loads: lane ln reads float4 at row*512 + ln*4 (h-half 0) and
// row*512 + 256 + ln*4 (h-half 1). Every wave load instruction is a dense
// 1KB run of 16 x 64B segments (R1-R4 used ln*8 +0/+4 -> 16B-used-per-32B
// holes -> 2x segment count -> ~2.4 TB/s cap; this is the single change).
__global__ __launch_bounds__(256) void k1_partials(
    const float* __restrict__ dec, const float* __restrict__ aw,
    const float* __restrict__ abp,
    float* __restrict__ ctx_part, float* __restrict__ l_part)
{
  const int chunk = blockIdx.x;
  const int b     = blockIdx.y;
  const int tid   = threadIdx.x;
  const int wv = tid >> 6, ln = tid & 63;
  const float ab = abp[0];
  const float4 aw0 = *(const float4*)(aw + ln*4);          // h in [0,256)
  const float4 aw1 = *(const float4*)(aw + 256 + ln*4);    // h in [256,512)

  const size_t rowstep = (size_t)BB*HH;
  const float* base = dec + ((size_t)(chunk*TPC + wv*16)*BB + b)*HH + (size_t)ln*4;

  float4 c0 = make_float4(0.f,0.f,0.f,0.f), c1 = make_float4(0.f,0.f,0.f,0.f);
  float l = 0.f;

  for (int it = 0; it < 16; it += 2) {
    const float* p0 = base + (size_t)it*rowstep;
    const float* p1 = base + (size_t)(it+1)*rowstep;
    const float4 xa0 = *(const float4*)(p0);
    const float4 xa1 = *(const float4*)(p0 + 256);
    const float4 xb0 = *(const float4*)(p1);
    const float4 xb1 = *(const float4*)(p1 + 256);
    float da = dot4(xa0, aw0) + dot4(xa1, aw1);
    float db = dot4(xb0, aw0) + dot4(xb1, aw1);
    #pragma unroll
    for (int off = 32; off > 0; off >>= 1) {   // 2 interleaved butterflies
      da += __shfl_xor(da, off);
      db += __shfl_xor(db, off);
    }
    const float exa = __expf(2.f*(da + ab));
    const float exb = __expf(2.f*(db + ab));
    const float tha = 1.f - 2.f*__builtin_amdgcn_rcpf(exa + 1.f);
    const float thb = 1.f - 2.f*__builtin_amdgcn_rcpf(exb + 1.f);
    const float wa = __expf(tha);
    const float wb = __expf(thb);
    l += wa + wb;
    c0.x = fmaf(wa, xa0.x, fmaf(wb, xb0.x, c0.x));
    c0.y = fmaf(wa, xa0.y, fmaf(wb, xb0.y, c0.y));
    c0.z = fmaf(wa, xa0.z, fmaf(wb, xb0.z, c0.z));
    c0.w = fmaf(wa, xa0.w, fmaf(wb, xb0.w, c0.w));
    c1.x = fmaf(wa, xa1.x, fmaf(wb, xb1.x, c1.x));
    c1.y = fmaf(wa, xa1.y, fmaf(wb, xb1.y, c1.y));
    c1.z = fmaf(wa, xa1.z, fmaf(wb, xb1.z, c1.z));
    c1.w = fmaf(wa, xa1.w, fmaf(wb, xb1.w, c1.w));
  }

  __shared__ float s_ctx[4][HH];
  __shared__ float s_l[4];
  *(float4*)&s_ctx[wv][ln*4]       = c0;
  *(float4*)&s_ctx[wv][256 + ln*4] = c1;
  if (ln == 0) s_l[wv] = l;
  __syncthreads();
  if (tid < 128) {
    const int h = tid * 4;
    float4 a = make_float4(0.f,0.f,0.f,0.f);
    #pragma unroll
    for (int w2 = 0; w2 < 4; ++w2) {
      const float4 v = *(const float4*)&s_ctx[w2][h];
      a.x += v.x; a.y += v.y; a.z += v.z; a.w += v.w;
    }
    const size_t pp = (size_t)b*NCHUNK + chunk;
    *(float4*)(ctx_part + pp*HH + h) = a;
    if (tid == 0) l_part[pp] = s_l[0] + s_l[1] + s_l[2] + s_l[3];
  }
}

// ---------------- k2: combine partials -> normalized context ----------------
__global__ __launch_bounds__(128) void k2_combine(
    const float* __restrict__ ctx_part, const float* __restrict__ l_part,
    float* __restrict__ ctx)
{
  const int b = blockIdx.x;
  const int h = threadIdx.x * 4;
  float L = 0.f;
  for (int p = 0; p < NCHUNK; ++p) L += l_part[b*NCHUNK + p];
  float4 a = make_float4(0.f,0.f,0.f,0.f);
  for (int p = 0; p < NCHUNK; ++p) {
    const float4 v = *(const float4*)(ctx_part + ((size_t)b*NCHUNK + p)*HH + h);
    a.x += v.x; a.y += v.y; a.z += v.z; a.w += v.w;
  }
  const float inv = 1.f / L;
  *(float4*)(ctx + b*HH + h) = make_float4(a.x*inv, a.y*inv, a.z*inv, a.w*inv);
}

// ---------------- k3: out = ctx @ out_w^T (partials over h-halves) ----------
__global__ __launch_bounds__(128) void k3_matmul(
    const float* __restrict__ ctx, const float* __restrict__ ow,
    float* __restrict__ out_part)
{
  const int c = blockIdx.x * 128 + threadIdx.x;
  const int half = blockIdx.y;            // h in [half*256, half*256+256)
  const int h0 = half * 256;
  const float* wrow = ow + (size_t)c * HH + h0;
  const float* cb = ctx + h0;             // uniform across block
  float acc[BB];
  #pragma unroll
  for (int b = 0; b < BB; ++b) acc[b] = 0.f;
  for (int hh = 0; hh < 256; hh += 4) {
    const float4 w4 = *(const float4*)(wrow + hh);
    #pragma unroll
    for (int b = 0; b < BB; ++b) {
      const float4 c4 = *(const float4*)(cb + (size_t)b*HH + hh);
      acc[b] = fmaf(w4.w, c4.w, fmaf(w4.z, c4.z, fmaf(w4.y, c4.y, fmaf(w4.x, c4.x, acc[b]))));
    }
  }
  float* op = out_part + (size_t)half * ((size_t)BB*CC);
  #pragma unroll
  for (int b = 0; b < BB; ++b) op[(size_t)b*CC + c] = acc[b];
}

// ---------------- k4: sum halves + bias -> d_out ---------------------------
__global__ __launch_bounds__(256) void k4_final(
    const float* __restrict__ out_part, const float* __restrict__ ob,
    float* __restrict__ out)
{
  const size_t i = ((size_t)blockIdx.x * 256 + threadIdx.x) * 4;
  const float4 p0 = *(const float4*)(out_part + i);
  const float4 p1 = *(const float4*)(out_part + (size_t)BB*CC + i);
  const int cIdx = (int)(i % CC);
  const float4 b4 = *(const float4*)(ob + cIdx);
  const float4 r = make_float4(p0.x+p1.x+b4.x, p0.y+p1.y+b4.y,
                               p0.z+p1.z+b4.z, p0.w+p1.w+b4.w);
  *(float4*)(out + i) = r;
}

extern "C" void kernel_launch(void* const* d_in, const int* in_sizes, int n_in,
                              void* d_out, int out_size, void* d_ws, size_t ws_size,
                              hipStream_t stream) {
  const float* dec = (const float*)d_in[0];
  const float* aw  = (const float*)d_in[1];
  const float* ab  = (const float*)d_in[2];
  const float* ow  = (const float*)d_in[3];
  const float* ob  = (const float*)d_in[4];
  float* out = (float*)d_out;
  float* ws  = (float*)d_ws;
  float* ctx   = ws + WS_CTX;
  float* lpart = ws + WS_LPART;
  float* big   = ws + WS_BIG;   // ctx_part for k1/k2, reused as out_part for k3/k4

  k1_partials<<<dim3(NCHUNK, BB), 256, 0, stream>>>(dec, aw, ab, big, lpart);
  k2_combine<<<dim3(BB), 128, 0, stream>>>(big, lpart, ctx);
  k3_matmul<<<dim3(CC/128, 2), 128, 0, stream>>>(ctx, ow, big);
  k4_final<<<dim3((BB*CC)/(256*4)), 256, 0, stream>>>(big, ob, out);
}